// Round 4
// baseline (1673.297 us; speedup 1.0000x reference)
//
#include <hip/hip_runtime.h>
#include <hip/hip_bf16.h>

#define B_  32
#define H_  8
#define L_  4096
#define D_  64
#define BH_ 256
#define U_  45
#define UP_ 48

typedef float f32x4  __attribute__((ext_vector_type(4)));
typedef short bf16x8 __attribute__((ext_vector_type(8)));

__device__ __forceinline__ unsigned short f2bf(float f) {
  unsigned u = __builtin_bit_cast(unsigned, f);
  u += 0x7fffu + ((u >> 16) & 1u);   // RNE; inputs finite
  return (unsigned short)(u >> 16);
}

#define WAITV(N) asm volatile("s_waitcnt vmcnt(" #N ")" ::: "memory")
#define SCHEDB() __builtin_amdgcn_sched_barrier(0)

// ---------------------------------------------------------------------------
// Kernel 1: M[bh][q] = max_j(Q·K[idx_j]) - mean_j(Q·K[idx_j]), f32.
// One wave per block; 8 queries per wave. Per query: DMA-gather 48 K-rows
// (12 KB) into a double-buffered LDS tile via global_load_lds (16B/lane; no
// VGPR staging -> no spills, pipeline depth lives in the vmcnt FIFO, not the
// register allocator). Global-source XOR pre-swizzle (slot = sig^(r&7), LDS
// dest linear per the gload_lds constraint) makes the compute read
// (lane j -> row j, slot g^(j&7)) bank-uniform. Compute: lane = one row,
// full dot in-lane (16 ds_read_b128 + 64 fma), Q broadcast from LDS, one
// 12-shfl reduction per query. Hand-counted vmcnt (never 0 mid-loop).
// XCD-affine bh ordering keeps each XCD's K gather L2-resident.
// ---------------------------------------------------------------------------
__global__ __launch_bounds__(64) void k_probM(
    const float* __restrict__ Qg, const float* __restrict__ Kg,
    const int* __restrict__ idxg, float* __restrict__ Mg)
{
  const int blk   = blockIdx.x;          // 131072 blocks
  const int xcd   = blk & 7;
  const int rr    = blk >> 3;            // 0..16383
  const int bhi   = rr >> 9;             // 0..31
  const int chunk = rr & 511;            // 0..511
  const int bh    = xcd + (bhi << 3);
  const int q0    = chunk * 8;

  const int lane = threadIdx.x;          // 0..63
  const int sig  = lane & 15;            // 16B slot within a row-group load
  const int rgrp = lane >> 4;            // which of 4 rows this lane stages
  const int jrow = (lane < U_) ? lane : (U_ - 1);   // compute: lane -> row
  const int jx   = jrow & 7;
  const int idxlane = (lane < U_) ? lane : (U_ - 1);

  __shared__ float kbuf0[48 * 64];       // 12 KB staging buffer A
  __shared__ float kbuf1[48 * 64];       // 12 KB staging buffer B
  __shared__ float qbuf[64];             // Q row broadcast tile

  const float* Kb = Kg + (size_t)bh * (L_ * D_);
  const float* Qb = Qg + (size_t)bh * (L_ * D_);

#define PREF(IDXV, QV, QABS) do { \
    (IDXV) = idxg[(size_t)(QABS) * U_ + idxlane]; \
    (QV)   = *(const f32x4*)(Qb + (size_t)(QABS) * D_ + (sig << 2)); \
  } while (0)

#define STAGE(BUF, IDXV) do { \
    _Pragma("unroll") \
    for (int g = 0; g < 12; g++) { \
      const int r_  = 4 * g + rgrp; \
      const int rc_ = (r_ < U_) ? r_ : (U_ - 1); \
      const int kid = __shfl((IDXV), rc_); \
      const int c_  = sig ^ (r_ & 7); \
      const float* gp_ = Kb + (size_t)kid * D_ + (c_ << 2); \
      __builtin_amdgcn_global_load_lds( \
          (const __attribute__((address_space(1))) void*)gp_, \
          (__attribute__((address_space(3))) void*)((BUF) + g * 256), \
          16, 0, 0); \
    } \
  } while (0)

#define COMPUTE(BUF, QV, QI) do { \
    if (lane < 16) *(f32x4*)(qbuf + (sig << 2)) = (QV); \
    float dacc = 0.f; \
    _Pragma("unroll") \
    for (int g = 0; g < 16; g++) { \
      f32x4 kv = *(const f32x4*)((BUF) + jrow * 64 + ((g ^ jx) << 2)); \
      f32x4 qq = *(const f32x4*)(qbuf + (g << 2)); \
      dacc = fmaf(kv[0], qq[0], dacc); \
      dacc = fmaf(kv[1], qq[1], dacc); \
      dacc = fmaf(kv[2], qq[2], dacc); \
      dacc = fmaf(kv[3], qq[3], dacc); \
    } \
    float mxv = (lane < U_) ? dacc : -3.4e38f; \
    float smv = (lane < U_) ? dacc : 0.f; \
    _Pragma("unroll") \
    for (int off = 1; off < 64; off <<= 1) { \
      mxv = fmax(mxv, __shfl_xor(mxv, off)); \
      smv += __shfl_xor(smv, off); \
    } \
    if (lane == 0) Mg[(size_t)bh * L_ + q0 + (QI)] = mxv - smv * (1.0f / 45.0f); \
  } while (0)

  // ---- prologue: pref(q0), wait, pref(q1), stage(q0)
  int   idxT; f32x4 qvT;
  PREF(idxT, qvT, q0 + 0);
  WAITV(0);
  SCHEDB();
  f32x4 qvC = qvT;                       // qv for the query being computed
  int   idxS = idxT;                     // idx for the query being staged
  int   idxN; f32x4 qvN;
  PREF(idxN, qvN, q0 + 1);
  SCHEDB();
  STAGE(kbuf0, idxS);
  SCHEDB();

  // FIFO at loop top (steady, qi>=1): [pref:2][stage(qi):12][store:1] = 15
#pragma unroll
  for (int qi = 0; qi < 8; qi++) {
    float* bufC = (qi & 1) ? kbuf1 : kbuf0;   // compute buffer
    float* bufS = (qi & 1) ? kbuf0 : kbuf1;   // stage buffer (next query)

    if (qi == 0)      { WAITV(12); }     // retire pref(q1)   [14 -> 12]
    else if (qi < 7)  { WAITV(13); }     // retire pref(q+1)  [15 -> 13]
    SCHEDB();
    int   idxStage = idxN;               // ready now
    f32x4 qvNext   = qvN;

    if (qi < 6) { PREF(idxN, qvN, q0 + qi + 2); SCHEDB(); }
    if (qi < 7) { STAGE(bufS, idxStage); SCHEDB(); }

    if (qi < 6)       { WAITV(14); }     // retire stage(qi): [26/27 -> 14]
    else if (qi == 6) { WAITV(12); }     // [25 -> 12]
    else              { WAITV(0);  }     // last buffer
    SCHEDB();

    COMPUTE(bufC, qvC, qi);
    SCHEDB();
    qvC = qvNext;
  }

#undef PREF
#undef STAGE
#undef COMPUTE
}

// ---------------------------------------------------------------------------
// Kernel 2: top-45 indices per (b,h) via 45 iterative block argmax passes.
// Writes 48 entries (3 pads = sels[0], harmlessly recomputed in k_attn).
// ---------------------------------------------------------------------------
__global__ __launch_bounds__(256) void k_top45(
    const float* __restrict__ Mg, int* __restrict__ qselg)
{
  __shared__ float mv[L_];
  __shared__ float rv[256];
  __shared__ int   ri[256];
  __shared__ int   sels[UP_];
  const int bh = blockIdx.x, t = threadIdx.x;

  for (int i = t; i < L_; i += 256) mv[i] = Mg[(size_t)bh * L_ + i];
  __syncthreads();

  for (int it = 0; it < U_; it++) {
    float bv = -3.4e38f; int bi = 0;
    for (int i = t; i < L_; i += 256) {
      float v = mv[i];
      if (v > bv) { bv = v; bi = i; }
    }
    rv[t] = bv; ri[t] = bi;
    __syncthreads();
    for (int s = 128; s > 0; s >>= 1) {
      if (t < s) {
        float ov = rv[t + s];
        if (ov > rv[t] || (ov == rv[t] && ri[t + s] < ri[t])) {
          rv[t] = ov; ri[t] = ri[t + s];
        }
      }
      __syncthreads();
    }
    if (t == 0) { sels[it] = ri[0]; mv[ri[0]] = -3.4e38f; }
    __syncthreads();
  }
  if (t == 0) { sels[45] = sels[0]; sels[46] = sels[0]; sels[47] = sels[0]; }
  __syncthreads();
  if (t < UP_) qselg[bh * UP_ + t] = sels[t];
}

// ---------------------------------------------------------------------------
// Kernel 3: context = cumsum(V, axis=L), written transposed to out[b,l,h,d].
// 8 L-segments x 64 dims per block; two-pass (seg sums -> prefixed scan).
// ---------------------------------------------------------------------------
__global__ __launch_bounds__(512) void k_cumsum(
    const float* __restrict__ Vg, float* __restrict__ out)
{
  const int bh = blockIdx.x, b = bh >> 3, h = bh & 7;
  const int d = threadIdx.x & 63, s = threadIdx.x >> 6;   // 8 segs x 512 rows
  __shared__ float segsum[8][64];

  const float* vb = Vg + (size_t)bh * L_ * D_ + d;
  const int l0 = s * 512;

  float acc = 0.f;
  for (int l = l0; l < l0 + 512; l += 4) {
    float a0 = vb[(size_t)(l + 0) * D_];
    float a1 = vb[(size_t)(l + 1) * D_];
    float a2 = vb[(size_t)(l + 2) * D_];
    float a3 = vb[(size_t)(l + 3) * D_];
    acc += a0; acc += a1; acc += a2; acc += a3;
  }
  segsum[s][d] = acc;
  __syncthreads();

  float run = 0.f;
  for (int ss = 0; ss < s; ss++) run += segsum[ss][d];

  float* ob = out + ((size_t)b * L_ * H_ + h) * D_ + d;
  for (int l = l0; l < l0 + 512; l += 4) {
    float a0 = vb[(size_t)(l + 0) * D_];
    float a1 = vb[(size_t)(l + 1) * D_];
    float a2 = vb[(size_t)(l + 2) * D_];
    float a3 = vb[(size_t)(l + 3) * D_];
    run += a0; ob[(size_t)(l + 0) * (H_ * D_)] = run;
    run += a1; ob[(size_t)(l + 1) * (H_ * D_)] = run;
    run += a2; ob[(size_t)(l + 2) * (H_ * D_)] = run;
    run += a3; ob[(size_t)(l + 3) * (H_ * D_)] = run;
  }
}

// ---------------------------------------------------------------------------
// Kernel 4: flash attention for the 45 selected rows per (b,h), bf16 MFMA.
// 8 waves split the 4096 keys (512 each); per-wave online softmax; P is
// moved C-frag -> A-frag through a padded per-wave LDS buffer; deterministic
// barrier-serialized cross-wave combine; overwrite rows of `out`.
// mask value -1e30; dead-row guard: p *= (m_row > -1e29).
// ---------------------------------------------------------------------------
__global__ __launch_bounds__(512, 2) void k_attn(
    const float* __restrict__ Qg, const float* __restrict__ Kg,
    const float* __restrict__ Vg, const int* __restrict__ qselg,
    float* __restrict__ out)
{
  const int bh = blockIdx.x, b = bh >> 3, h = bh & 7;
  const int wave = threadIdx.x >> 6, lane = threadIdx.x & 63;
  const int l15 = lane & 15, l4 = lane >> 4;

  __shared__ int   qs[UP_];
  __shared__ float mw[8][UP_];
  __shared__ float lw[8][UP_];
  __shared__ float lgf[UP_];
  __shared__ float Osum[UP_][64];
  __shared__ unsigned short Pl[8][16][72];   // per-wave P tile, padded stride 72

  if (threadIdx.x < UP_) qs[threadIdx.x] = qselg[bh * UP_ + threadIdx.x];
  for (int i = threadIdx.x; i < UP_ * 64; i += 512) (&Osum[0][0])[i] = 0.f;
  __syncthreads();

  int qmax = 0;
  for (int r2 = 0; r2 < UP_; r2++) qmax = max(qmax, qs[r2]);

  const float* Qb = Qg + (size_t)bh * L_ * D_;
  const float* Kb = Kg + (size_t)bh * L_ * D_;
  const float* Vb = Vg + (size_t)bh * L_ * D_;

  // A-frags: Q rows gathered at qsel. A[row=l15][k=(l4)*8+j]
  bf16x8 aq[3][2];
#pragma unroll
  for (int mf = 0; mf < 3; mf++) {
    const float* src = Qb + (size_t)qs[mf * 16 + l15] * D_ + l4 * 8;
#pragma unroll
    for (int ks = 0; ks < 2; ks++) {
      bf16x8 a;
#pragma unroll
      for (int j = 0; j < 8; j++) a[j] = (short)f2bf(src[ks * 32 + j]);
      aq[mf][ks] = a;
    }
  }

  int myq[3][4];
#pragma unroll
  for (int mf = 0; mf < 3; mf++)
#pragma unroll
    for (int rg = 0; rg < 4; rg++)
      myq[mf][rg] = qs[mf * 16 + l4 * 4 + rg];

  float m_r[3][4], l_r[3][4];
  f32x4 Oa[3][4];
  const f32x4 z4 = {0.f, 0.f, 0.f, 0.f};
#pragma unroll
  for (int mf = 0; mf < 3; mf++)
#pragma unroll
    for (int rg = 0; rg < 4; rg++) { m_r[mf][rg] = -1e30f; l_r[mf][rg] = 0.f; }
#pragma unroll
  for (int mf = 0; mf < 3; mf++)
#pragma unroll
    for (int df = 0; df < 4; df++) Oa[mf][df] = z4;

  for (int t = 0; t < 8; t++) {
    const int k0 = wave * 512 + t * 64;
    if (k0 > qmax) break;   // k0 ascending per wave; uniform within wave

    // ---- S = (Q K^T): B[kdim=d][col=key] = K[key][d]
    f32x4 S[3][4];
#pragma unroll
    for (int nf = 0; nf < 4; nf++) {
      const float* ksrc = Kb + (size_t)(k0 + nf * 16 + l15) * D_ + l4 * 8;
      bf16x8 bk0, bk1;
#pragma unroll
      for (int j = 0; j < 8; j++) bk0[j] = (short)f2bf(ksrc[j]);
#pragma unroll
      for (int j = 0; j < 8; j++) bk1[j] = (short)f2bf(ksrc[32 + j]);
#pragma unroll
      for (int mf = 0; mf < 3; mf++) {
        f32x4 c = z4;
        c = __builtin_amdgcn_mfma_f32_16x16x32_bf16(aq[mf][0], bk0, c, 0, 0, 0);
        c = __builtin_amdgcn_mfma_f32_16x16x32_bf16(aq[mf][1], bk1, c, 0, 0, 0);
        S[mf][nf] = c;
      }
    }

    // ---- scale + causal mask (col > qsel[row] -> -1e30)
#pragma unroll
    for (int mf = 0; mf < 3; mf++)
#pragma unroll
      for (int nf = 0; nf < 4; nf++) {
        const int kc = k0 + nf * 16 + l15;
#pragma unroll
        for (int rg = 0; rg < 4; rg++) {
          float v = S[mf][nf][rg] * 0.125f;
          S[mf][nf][rg] = (kc > myq[mf][rg]) ? -1e30f : v;
        }
      }

    // ---- V B-frags for this tile (shared across mf)
    bf16x8 vv[2][4];
#pragma unroll
    for (int ks = 0; ks < 2; ks++)
#pragma unroll
      for (int df = 0; df < 4; df++) {
        bf16x8 x;
#pragma unroll
        for (int j = 0; j < 8; j++)
          x[j] = (short)f2bf(Vb[(size_t)(k0 + ks * 32 + l4 * 8 + j) * D_ + df * 16 + l15]);
        vv[ks][df] = x;
      }

#pragma unroll
    for (int mf = 0; mf < 3; mf++) {
      // online-softmax stats update (row lives in 16 consecutive lanes)
#pragma unroll
      for (int rg = 0; rg < 4; rg++) {
        float tm = fmax(fmax(S[mf][0][rg], S[mf][1][rg]),
                        fmax(S[mf][2][rg], S[mf][3][rg]));
#pragma unroll
        for (int off = 1; off < 16; off <<= 1) tm = fmax(tm, __shfl_xor(tm, off));
        const float mn = fmax(m_r[mf][rg], tm);
        const float sc = __expf(m_r[mf][rg] - mn);   // (-1e30)-(-1e30)=0 -> 1
        l_r[mf][rg] *= sc;
#pragma unroll
        for (int df = 0; df < 4; df++) Oa[mf][df][rg] *= sc;
        m_r[mf][rg] = mn;
      }

      // p = exp(S - m), dead-row guarded; write P tile (C-layout) to LDS
      float rs[4] = {0.f, 0.f, 0.f, 0.f};
#pragma unroll
      for (int nf = 0; nf < 4; nf++)
#pragma unroll
        for (int rg = 0; rg < 4; rg++) {
          float p = __expf(S[mf][nf][rg] - m_r[mf][rg]);
          p = (m_r[mf][rg] > -1e29f) ? p : 0.f;
          rs[rg] += p;
          Pl[wave][l4 * 4 + rg][nf * 16 + l15] = f2bf(p);
        }
#pragma unroll
      for (int rg = 0; rg < 4; rg++) {
        float r = rs[rg];
#pragma unroll
        for (int off = 1; off < 16; off <<= 1) r += __shfl_xor(r, off);
        l_r[mf][rg] += r;
      }

      // PV: A-frag read back from LDS (row=l15, k=(l4)*8+j), accumulate O
#pragma unroll
      for (int ks = 0; ks < 2; ks++) {
        const bf16x8 pa = *(const bf16x8*)(&Pl[wave][l15][ks * 32 + l4 * 8]);
#pragma unroll
        for (int df = 0; df < 4; df++)
          Oa[mf][df] = __builtin_amdgcn_mfma_f32_16x16x32_bf16(pa, vv[ks][df], Oa[mf][df], 0, 0, 0);
      }
    }
  }

  // ---- cross-wave combine (deterministic)
  if (l15 == 0) {
#pragma unroll
    for (int mf = 0; mf < 3; mf++)
#pragma unroll
      for (int rg = 0; rg < 4; rg++) {
        const int row = mf * 16 + l4 * 4 + rg;
        mw[wave][row] = m_r[mf][rg];
        lw[wave][row] = l_r[mf][rg];
      }
  }
  __syncthreads();

  float sc_me[3][4];
#pragma unroll
  for (int mf = 0; mf < 3; mf++)
#pragma unroll
    for (int rg = 0; rg < 4; rg++) {
      const int row = mf * 16 + l4 * 4 + rg;
      float m = -1e30f;
#pragma unroll
      for (int w = 0; w < 8; w++) m = fmax(m, mw[w][row]);
      float ls = 0.f;
#pragma unroll
      for (int w = 0; w < 8; w++) ls += lw[w][row] * __expf(mw[w][row] - m);
      sc_me[mf][rg] = __expf(m_r[mf][rg] - m);   // 0 for dead waves
      if (wave == 0 && l15 == 0) lgf[row] = ls;
    }

  for (int w = 0; w < 8; w++) {
    __syncthreads();
    if (wave == w) {
#pragma unroll
      for (int mf = 0; mf < 3; mf++)
#pragma unroll
        for (int df = 0; df < 4; df++)
#pragma unroll
          for (int rg = 0; rg < 4; rg++)
            Osum[mf * 16 + l4 * 4 + rg][df * 16 + l15] += Oa[mf][df][rg] * sc_me[mf][rg];
    }
  }
  __syncthreads();

  for (int i = threadIdx.x; i < U_ * 64; i += 512) {
    const int r = i >> 6, d = i & 63;
    out[(((size_t)b * L_ + (size_t)qs[r]) * H_ + h) * D_ + d] = Osum[r][d] / lgf[r];
  }
}

// ---------------------------------------------------------------------------
extern "C" void kernel_launch(void* const* d_in, const int* in_sizes, int n_in,
                              void* d_out, int out_size, void* d_ws, size_t ws_size,
                              hipStream_t stream)
{
  const float* Q   = (const float*)d_in[0];
  const float* K   = (const float*)d_in[1];
  const float* V   = (const float*)d_in[2];
  const int*   idx = (const int*)d_in[3];
  float* out = (float*)d_out;

  const size_t m_bytes = (size_t)BH_ * L_ * sizeof(float);   // 4 MiB
  float* M    = (float*)d_ws;
  int*   qsel = (int*)((char*)d_ws + m_bytes);
  if (ws_size < m_bytes + (size_t)BH_ * UP_ * sizeof(int)) return;

  k_probM <<<131072, 64, 0, stream>>>(Q, K, idx, M);
  k_top45 <<<BH_,    256, 0, stream>>>(M, qsel);
  k_cumsum<<<BH_,    512, 0, stream>>>(V, out);
  k_attn  <<<BH_,    512, 0, stream>>>(Q, K, V, qsel, out);
}

// Round 6
// 1499.701 us; speedup vs baseline: 1.1158x; 1.1158x over previous
//
#include <hip/hip_runtime.h>
#include <hip/hip_bf16.h>

#define B_  32
#define H_  8
#define L_  4096
#define D_  64
#define BH_ 256
#define U_  45
#define UP_ 48

typedef float f32x4  __attribute__((ext_vector_type(4)));
typedef short bf16x8 __attribute__((ext_vector_type(8)));

__device__ __forceinline__ unsigned short f2bf(float f) {
  unsigned u = __builtin_bit_cast(unsigned, f);
  u += 0x7fffu + ((u >> 16) & 1u);   // RNE; inputs finite
  return (unsigned short)(u >> 16);
}

// ---------------------------------------------------------------------------
// Kernel 1: M[bh][q] = max_j(Q·K[idx_j]) - mean_j(Q·K[idx_j]), f32.
// Quad (4 lanes) per query; lane owns 16 of 64 dims (4 f32x4) -> each K row
// is one fully-coalesced 256B quad read. Plain-C 2-row ping-pong (A/B, 4 rows
// = 64 VGPRs of K data): while dotting one buffer the other's 8 dwordx4 are
// in flight. Indices staged once per block into LDS (padded stride 65) and
// fetched one group ahead into registers, so the serial chain per row is just
// the K load. No inline asm: compiler computes its own (correct) waitcnts.
// __launch_bounds__(256,3): VGPR cap ~170 -- big enough not to sink loads
// (R2 failure @36), small enough not to spill (R3 failure: 160 live @128cap).
// XCD-affine bh ordering keeps each XCD's K gather L2-resident (~1MB/bh).
// ---------------------------------------------------------------------------
__global__ __launch_bounds__(256, 3) void k_probM(
    const float* __restrict__ Qg, const float* __restrict__ Kg,
    const int* __restrict__ idxg, float* __restrict__ Mg)
{
  const int blk   = blockIdx.x;          // 16384 blocks
  const int xcd   = blk & 7;
  const int rr    = blk >> 3;
  const int bhi   = rr >> 6;             // 0..31
  const int chunk = rr & 63;             // 0..63
  const int bh    = xcd + (bhi << 3);
  const int q0    = chunk * 64;
  const int quad  = threadIdx.x >> 2;    // 0..63
  const int lq    = threadIdx.x & 3;
  const int q     = q0 + quad;

  // idx staged [j][quad] with padded row stride 65: flat-coalesced global
  // reads, conflict-free LDS writes (bank = (65j+qq)%32 spreads over j) and
  // broadcast reads (16 consecutive addrs x 4-lane broadcast).
  __shared__ int sidx[U_][65];
  for (int i = threadIdx.x; i < 64 * U_; i += 256) {
    const int qq = i / U_, j = i - qq * U_;
    sidx[j][qq] = idxg[(size_t)q0 * U_ + i];
  }
  __syncthreads();

  const float* qrow = Qg + ((size_t)bh * L_ + q) * D_ + lq * 16;
  f32x4 qv[4];
#pragma unroll
  for (int c = 0; c < 4; c++) qv[c] = *(const f32x4*)(qrow + 4 * c);

  const float* kb = Kg + (size_t)bh * (L_ * D_) + lq * 16;

#define LOADROW(R, ID) do { \
    const float* kr_ = kb + ((size_t)(ID) << 6); \
    R[0] = *(const f32x4*)(kr_);      R[1] = *(const f32x4*)(kr_ + 4); \
    R[2] = *(const f32x4*)(kr_ + 8);  R[3] = *(const f32x4*)(kr_ + 12); \
  } while (0)

#define DOTROW(R) do { \
    float e0_ = 0.f, e1_ = 0.f; \
    _Pragma("unroll") \
    for (int c_ = 0; c_ < 4; c_++) { \
      e0_ = fmaf(qv[c_][0], R[c_][0], e0_); \
      e1_ = fmaf(qv[c_][1], R[c_][1], e1_); \
      e0_ = fmaf(qv[c_][2], R[c_][2], e0_); \
      e1_ = fmaf(qv[c_][3], R[c_][3], e1_); \
    } \
    float d_ = e0_ + e1_; \
    d_ += __shfl_xor(d_, 1); \
    d_ += __shfl_xor(d_, 2); \
    mx = fmax(mx, d_); sm += d_; \
  } while (0)

  // rows: iter t consumes A={4t,4t+1}, B={4t+2,4t+3}; 11 iters = rows 0..43;
  // tail row 44 is left in A0 by the last prefetch (clamped ids).
  int idA0 = sidx[0][quad], idA1 = sidx[1][quad];
  int idB0 = sidx[2][quad], idB1 = sidx[3][quad];

  f32x4 A0[4], A1[4], B0[4], B1[4];
  LOADROW(A0, idA0);
  LOADROW(A1, idA1);

  float mx = -3.4e38f, sm = 0.f;
#pragma unroll 1
  for (int t = 0; t < 11; t++) {
    LOADROW(B0, idB0);
    LOADROW(B1, idB1);
    const int ga = 4 * t + 4, gb = 4 * t + 5;
    const int nA0 = sidx[ga < U_ ? ga : U_ - 1][quad];
    const int nA1 = sidx[gb < U_ ? gb : U_ - 1][quad];
    DOTROW(A0);
    DOTROW(A1);
    LOADROW(A0, nA0);
    LOADROW(A1, nA1);
    const int gc = 4 * t + 6, gd = 4 * t + 7;
    idB0 = sidx[gc < U_ ? gc : U_ - 1][quad];
    idB1 = sidx[gd < U_ ? gd : U_ - 1][quad];
    DOTROW(B0);
    DOTROW(B1);
  }
  DOTROW(A0);                            // row 44

#undef LOADROW
#undef DOTROW

  if (lq == 0) Mg[(size_t)bh * L_ + q] = mx - sm * (1.0f / 45.0f);
}

// ---------------------------------------------------------------------------
// Kernel 2: top-45 indices per (b,h) via 45 iterative block argmax passes.
// Writes 48 entries (3 pads = sels[0], harmlessly recomputed in k_attn).
// ---------------------------------------------------------------------------
__global__ __launch_bounds__(256) void k_top45(
    const float* __restrict__ Mg, int* __restrict__ qselg)
{
  __shared__ float mv[L_];
  __shared__ float rv[256];
  __shared__ int   ri[256];
  __shared__ int   sels[UP_];
  const int bh = blockIdx.x, t = threadIdx.x;

  for (int i = t; i < L_; i += 256) mv[i] = Mg[(size_t)bh * L_ + i];
  __syncthreads();

  for (int it = 0; it < U_; it++) {
    float bv = -3.4e38f; int bi = 0;
    for (int i = t; i < L_; i += 256) {
      float v = mv[i];
      if (v > bv) { bv = v; bi = i; }
    }
    rv[t] = bv; ri[t] = bi;
    __syncthreads();
    for (int s = 128; s > 0; s >>= 1) {
      if (t < s) {
        float ov = rv[t + s];
        if (ov > rv[t] || (ov == rv[t] && ri[t + s] < ri[t])) {
          rv[t] = ov; ri[t] = ri[t + s];
        }
      }
      __syncthreads();
    }
    if (t == 0) { sels[it] = ri[0]; mv[ri[0]] = -3.4e38f; }
    __syncthreads();
  }
  if (t == 0) { sels[45] = sels[0]; sels[46] = sels[0]; sels[47] = sels[0]; }
  __syncthreads();
  if (t < UP_) qselg[bh * UP_ + t] = sels[t];
}

// ---------------------------------------------------------------------------
// Kernel 3: context = cumsum(V, axis=L), written transposed to out[b,l,h,d].
// 8 L-segments x 64 dims per block; two-pass (seg sums -> prefixed scan).
// ---------------------------------------------------------------------------
__global__ __launch_bounds__(512) void k_cumsum(
    const float* __restrict__ Vg, float* __restrict__ out)
{
  const int bh = blockIdx.x, b = bh >> 3, h = bh & 7;
  const int d = threadIdx.x & 63, s = threadIdx.x >> 6;   // 8 segs x 512 rows
  __shared__ float segsum[8][64];

  const float* vb = Vg + (size_t)bh * L_ * D_ + d;
  const int l0 = s * 512;

  float acc = 0.f;
  for (int l = l0; l < l0 + 512; l += 4) {
    float a0 = vb[(size_t)(l + 0) * D_];
    float a1 = vb[(size_t)(l + 1) * D_];
    float a2 = vb[(size_t)(l + 2) * D_];
    float a3 = vb[(size_t)(l + 3) * D_];
    acc += a0; acc += a1; acc += a2; acc += a3;
  }
  segsum[s][d] = acc;
  __syncthreads();

  float run = 0.f;
  for (int ss = 0; ss < s; ss++) run += segsum[ss][d];

  float* ob = out + ((size_t)b * L_ * H_ + h) * D_ + d;
  for (int l = l0; l < l0 + 512; l += 4) {
    float a0 = vb[(size_t)(l + 0) * D_];
    float a1 = vb[(size_t)(l + 1) * D_];
    float a2 = vb[(size_t)(l + 2) * D_];
    float a3 = vb[(size_t)(l + 3) * D_];
    run += a0; ob[(size_t)(l + 0) * (H_ * D_)] = run;
    run += a1; ob[(size_t)(l + 1) * (H_ * D_)] = run;
    run += a2; ob[(size_t)(l + 2) * (H_ * D_)] = run;
    run += a3; ob[(size_t)(l + 3) * (H_ * D_)] = run;
  }
}

// ---------------------------------------------------------------------------
// Kernel 4: flash attention for the 45 selected rows per (b,h), bf16 MFMA.
// 8 waves split the 4096 keys (512 each); per-wave online softmax; P is
// moved C-frag -> A-frag through a padded per-wave LDS buffer; deterministic
// barrier-serialized cross-wave combine; overwrite rows of `out`.
// mask value -1e30; dead-row guard: p *= (m_row > -1e29).
// ---------------------------------------------------------------------------
__global__ __launch_bounds__(512, 2) void k_attn(
    const float* __restrict__ Qg, const float* __restrict__ Kg,
    const float* __restrict__ Vg, const int* __restrict__ qselg,
    float* __restrict__ out)
{
  const int bh = blockIdx.x, b = bh >> 3, h = bh & 7;
  const int wave = threadIdx.x >> 6, lane = threadIdx.x & 63;
  const int l15 = lane & 15, l4 = lane >> 4;

  __shared__ int   qs[UP_];
  __shared__ float mw[8][UP_];
  __shared__ float lw[8][UP_];
  __shared__ float lgf[UP_];
  __shared__ float Osum[UP_][64];
  __shared__ unsigned short Pl[8][16][72];   // per-wave P tile, padded stride 72

  if (threadIdx.x < UP_) qs[threadIdx.x] = qselg[bh * UP_ + threadIdx.x];
  for (int i = threadIdx.x; i < UP_ * 64; i += 512) (&Osum[0][0])[i] = 0.f;
  __syncthreads();

  int qmax = 0;
  for (int r2 = 0; r2 < UP_; r2++) qmax = max(qmax, qs[r2]);

  const float* Qb = Qg + (size_t)bh * L_ * D_;
  const float* Kb = Kg + (size_t)bh * L_ * D_;
  const float* Vb = Vg + (size_t)bh * L_ * D_;

  // A-frags: Q rows gathered at qsel. A[row=l15][k=(l4)*8+j]
  bf16x8 aq[3][2];
#pragma unroll
  for (int mf = 0; mf < 3; mf++) {
    const float* src = Qb + (size_t)qs[mf * 16 + l15] * D_ + l4 * 8;
#pragma unroll
    for (int ks = 0; ks < 2; ks++) {
      bf16x8 a;
#pragma unroll
      for (int j = 0; j < 8; j++) a[j] = (short)f2bf(src[ks * 32 + j]);
      aq[mf][ks] = a;
    }
  }

  int myq[3][4];
#pragma unroll
  for (int mf = 0; mf < 3; mf++)
#pragma unroll
    for (int rg = 0; rg < 4; rg++)
      myq[mf][rg] = qs[mf * 16 + l4 * 4 + rg];

  float m_r[3][4], l_r[3][4];
  f32x4 Oa[3][4];
  const f32x4 z4 = {0.f, 0.f, 0.f, 0.f};
#pragma unroll
  for (int mf = 0; mf < 3; mf++)
#pragma unroll
    for (int rg = 0; rg < 4; rg++) { m_r[mf][rg] = -1e30f; l_r[mf][rg] = 0.f; }
#pragma unroll
  for (int mf = 0; mf < 3; mf++)
#pragma unroll
    for (int df = 0; df < 4; df++) Oa[mf][df] = z4;

  for (int t = 0; t < 8; t++) {
    const int k0 = wave * 512 + t * 64;
    if (k0 > qmax) break;   // k0 ascending per wave; uniform within wave

    // ---- S = (Q K^T): B[kdim=d][col=key] = K[key][d]
    f32x4 S[3][4];
#pragma unroll
    for (int nf = 0; nf < 4; nf++) {
      const float* ksrc = Kb + (size_t)(k0 + nf * 16 + l15) * D_ + l4 * 8;
      bf16x8 bk0, bk1;
#pragma unroll
      for (int j = 0; j < 8; j++) bk0[j] = (short)f2bf(ksrc[j]);
#pragma unroll
      for (int j = 0; j < 8; j++) bk1[j] = (short)f2bf(ksrc[32 + j]);
#pragma unroll
      for (int mf = 0; mf < 3; mf++) {
        f32x4 c = z4;
        c = __builtin_amdgcn_mfma_f32_16x16x32_bf16(aq[mf][0], bk0, c, 0, 0, 0);
        c = __builtin_amdgcn_mfma_f32_16x16x32_bf16(aq[mf][1], bk1, c, 0, 0, 0);
        S[mf][nf] = c;
      }
    }

    // ---- scale + causal mask (col > qsel[row] -> -1e30)
#pragma unroll
    for (int mf = 0; mf < 3; mf++)
#pragma unroll
      for (int nf = 0; nf < 4; nf++) {
        const int kc = k0 + nf * 16 + l15;
#pragma unroll
        for (int rg = 0; rg < 4; rg++) {
          float v = S[mf][nf][rg] * 0.125f;
          S[mf][nf][rg] = (kc > myq[mf][rg]) ? -1e30f : v;
        }
      }

    // ---- V B-frags for this tile (shared across mf)
    bf16x8 vv[2][4];
#pragma unroll
    for (int ks = 0; ks < 2; ks++)
#pragma unroll
      for (int df = 0; df < 4; df++) {
        bf16x8 x;
#pragma unroll
        for (int j = 0; j < 8; j++)
          x[j] = (short)f2bf(Vb[(size_t)(k0 + ks * 32 + l4 * 8 + j) * D_ + df * 16 + l15]);
        vv[ks][df] = x;
      }

#pragma unroll
    for (int mf = 0; mf < 3; mf++) {
      // online-softmax stats update (row lives in 16 consecutive lanes)
#pragma unroll
      for (int rg = 0; rg < 4; rg++) {
        float tm = fmax(fmax(S[mf][0][rg], S[mf][1][rg]),
                        fmax(S[mf][2][rg], S[mf][3][rg]));
#pragma unroll
        for (int off = 1; off < 16; off <<= 1) tm = fmax(tm, __shfl_xor(tm, off));
        const float mn = fmax(m_r[mf][rg], tm);
        const float sc = __expf(m_r[mf][rg] - mn);   // (-1e30)-(-1e30)=0 -> 1
        l_r[mf][rg] *= sc;
#pragma unroll
        for (int df = 0; df < 4; df++) Oa[mf][df][rg] *= sc;
        m_r[mf][rg] = mn;
      }

      // p = exp(S - m), dead-row guarded; write P tile (C-layout) to LDS
      float rs[4] = {0.f, 0.f, 0.f, 0.f};
#pragma unroll
      for (int nf = 0; nf < 4; nf++)
#pragma unroll
        for (int rg = 0; rg < 4; rg++) {
          float p = __expf(S[mf][nf][rg] - m_r[mf][rg]);
          p = (m_r[mf][rg] > -1e29f) ? p : 0.f;
          rs[rg] += p;
          Pl[wave][l4 * 4 + rg][nf * 16 + l15] = f2bf(p);
        }
#pragma unroll
      for (int rg = 0; rg < 4; rg++) {
        float r = rs[rg];
#pragma unroll
        for (int off = 1; off < 16; off <<= 1) r += __shfl_xor(r, off);
        l_r[mf][rg] += r;
      }

      // PV: A-frag read back from LDS (row=l15, k=(l4)*8+j), accumulate O
#pragma unroll
      for (int ks = 0; ks < 2; ks++) {
        const bf16x8 pa = *(const bf16x8*)(&Pl[wave][l15][ks * 32 + l4 * 8]);
#pragma unroll
        for (int df = 0; df < 4; df++)
          Oa[mf][df] = __builtin_amdgcn_mfma_f32_16x16x32_bf16(pa, vv[ks][df], Oa[mf][df], 0, 0, 0);
      }
    }
  }

  // ---- cross-wave combine (deterministic)
  if (l15 == 0) {
#pragma unroll
    for (int mf = 0; mf < 3; mf++)
#pragma unroll
      for (int rg = 0; rg < 4; rg++) {
        const int row = mf * 16 + l4 * 4 + rg;
        mw[wave][row] = m_r[mf][rg];
        lw[wave][row] = l_r[mf][rg];
      }
  }
  __syncthreads();

  float sc_me[3][4];
#pragma unroll
  for (int mf = 0; mf < 3; mf++)
#pragma unroll
    for (int rg = 0; rg < 4; rg++) {
      const int row = mf * 16 + l4 * 4 + rg;
      float m = -1e30f;
#pragma unroll
      for (int w = 0; w < 8; w++) m = fmax(m, mw[w][row]);
      float ls = 0.f;
#pragma unroll
      for (int w = 0; w < 8; w++) ls += lw[w][row] * __expf(mw[w][row] - m);
      sc_me[mf][rg] = __expf(m_r[mf][rg] - m);   // 0 for dead waves
      if (wave == 0 && l15 == 0) lgf[row] = ls;
    }

  for (int w = 0; w < 8; w++) {
    __syncthreads();
    if (wave == w) {
#pragma unroll
      for (int mf = 0; mf < 3; mf++)
#pragma unroll
        for (int df = 0; df < 4; df++)
#pragma unroll
          for (int rg = 0; rg < 4; rg++)
            Osum[mf * 16 + l4 * 4 + rg][df * 16 + l15] += Oa[mf][df][rg] * sc_me[mf][rg];
    }
  }
  __syncthreads();

  for (int i = threadIdx.x; i < U_ * 64; i += 512) {
    const int r = i >> 6, d = i & 63;
    out[(((size_t)b * L_ + (size_t)qs[r]) * H_ + h) * D_ + d] = Osum[r][d] / lgf[r];
  }
}

// ---------------------------------------------------------------------------
extern "C" void kernel_launch(void* const* d_in, const int* in_sizes, int n_in,
                              void* d_out, int out_size, void* d_ws, size_t ws_size,
                              hipStream_t stream)
{
  const float* Q   = (const float*)d_in[0];
  const float* K   = (const float*)d_in[1];
  const float* V   = (const float*)d_in[2];
  const int*   idx = (const int*)d_in[3];
  float* out = (float*)d_out;

  const size_t m_bytes = (size_t)BH_ * L_ * sizeof(float);   // 4 MiB
  float* M    = (float*)d_ws;
  int*   qsel = (int*)((char*)d_ws + m_bytes);
  if (ws_size < m_bytes + (size_t)BH_ * UP_ * sizeof(int)) return;

  k_probM <<<16384, 256, 0, stream>>>(Q, K, idx, M);
  k_top45 <<<BH_,   256, 0, stream>>>(M, qsel);
  k_cumsum<<<BH_,   512, 0, stream>>>(V, out);
  k_attn  <<<BH_,   512, 0, stream>>>(Q, K, V, qsel, out);
}